// Round 1
// baseline (227.775 us; speedup 1.0000x reference)
//
#include <hip/hip_runtime.h>
#include <cstdint>

typedef __bf16 bf16x8 __attribute__((ext_vector_type(8)));
typedef float f32x4 __attribute__((ext_vector_type(4)));
typedef unsigned short u16;
typedef unsigned int u32;

__device__ __forceinline__ u16 f2bf(float f) {
    u32 u = __builtin_bit_cast(u32, f);
    u += 0x7fffu + ((u >> 16) & 1u);
    return (u16)(u >> 16);
}

__device__ __forceinline__ void gl_lds16(const u16* g, u16* l) {
    __builtin_amdgcn_global_load_lds(
        (const __attribute__((address_space(1))) void*)g,
        (__attribute__((address_space(3))) void*)l,
        16, 0, 0);
}

// ---------------- fp32 -> bf16 conversion (with zero padding past srcn) ----
__global__ void cvt_pad(const float* __restrict__ src, u16* __restrict__ dst,
                        int srcn, int totn) {
    int i = (blockIdx.x * 256 + threadIdx.x) * 4;
    if (i >= totn) return;
    float4 v = make_float4(0.f, 0.f, 0.f, 0.f);
    if (i < srcn) v = *(const float4*)&src[i];
    ushort4 o;
    o.x = f2bf(v.x); o.y = f2bf(v.y); o.z = f2bf(v.z); o.w = f2bf(v.w);
    *(ushort4*)&dst[i] = o;
}

// ---------------- bf16 GEMM: C[M,N] = A[M,K] @ W[N,K]^T + bias ------------
// m97 structure: 128x128 tile, BK=64, 4 waves (each 64x64), global_load_lds.
__device__ __forceinline__ void store_out(u16* C, long idx, float v) { C[idx] = f2bf(v); }
__device__ __forceinline__ void store_out(float* C, long idx, float v) { C[idx] = v; }

template <typename OutT>
__global__ __launch_bounds__(256) void gemm_bt(
    const u16* __restrict__ A, const u16* __restrict__ W,
    const float* __restrict__ bias, OutT* __restrict__ C,
    int M, int N, int K) {
    __shared__ u16 As[128 * 64];
    __shared__ u16 Bs[128 * 64];
    const int tid = threadIdx.x;
    const int w = tid >> 6, l = tid & 63;
    const int wr = w >> 1, wc = w & 1;
    const int l15 = l & 15, lg = l >> 4;
    const long tm = blockIdx.y, tn = blockIdx.x;
    const u16* Ab = A + tm * 128 * (long)K;
    const u16* Bb = W + tn * 128 * (long)K;

    f32x4 acc[4][4] = {};

    for (int k0 = 0; k0 < K; k0 += 64) {
#pragma unroll
        for (int t = 0; t < 4; ++t) {
            int i = t * 256 + tid;
            int row = i >> 3, cc = i & 7;
            gl_lds16(Ab + (long)row * K + k0 + cc * 8, &As[i * 8]);
            gl_lds16(Bb + (long)row * K + k0 + cc * 8, &Bs[i * 8]);
        }
        __syncthreads();
#pragma unroll
        for (int kk = 0; kk < 64; kk += 32) {
            bf16x8 a[4], b[4];
#pragma unroll
            for (int m = 0; m < 4; ++m)
                a[m] = *(const bf16x8*)&As[(wr * 64 + m * 16 + l15) * 64 + kk + lg * 8];
#pragma unroll
            for (int n = 0; n < 4; ++n)
                b[n] = *(const bf16x8*)&Bs[(wc * 64 + n * 16 + l15) * 64 + kk + lg * 8];
#pragma unroll
            for (int m = 0; m < 4; ++m)
#pragma unroll
                for (int n = 0; n < 4; ++n)
                    acc[m][n] = __builtin_amdgcn_mfma_f32_16x16x32_bf16(
                        a[m], b[n], acc[m][n], 0, 0, 0);
        }
        __syncthreads();
    }

    const long row0 = tm * 128 + wr * 64;
    const long col0 = tn * 128 + wc * 64;
#pragma unroll
    for (int m = 0; m < 4; ++m)
#pragma unroll
        for (int n = 0; n < 4; ++n)
#pragma unroll
            for (int r = 0; r < 4; ++r) {
                long row = row0 + m * 16 + lg * 4 + r;
                long col = col0 + n * 16 + l15;
                float v = acc[m][n][r] + bias[col];
                store_out(C, row * N + col, v);
            }
}

// ---------------- fused attention ------------------------------------------
// grid (ntile=32, h=16, b=4), 256 threads = 4 waves, each wave owns 32 Q rows.
__global__ __launch_bounds__(256) void attn_fused(
    const u16* __restrict__ Q,   // [B*4096, 1024] bf16
    const u16* __restrict__ Kb,  // [B*77 (pad 384), 1024] bf16
    const u16* __restrict__ Vb,  // same layout as Kb
    const float* __restrict__ mask,  // [B, 4096, 77] f32
    u16* __restrict__ Ao) {          // [B*4096, 1024] bf16
    __shared__ u16 Ks[96 * 64];   // K[t][d], t zero-padded to 96
    __shared__ u16 Vt[64 * 96];   // V^T[d][t]
    __shared__ u16 Ps[128 * 96];  // P bf16

    const int b = blockIdx.z, h = blockIdx.y, nt = blockIdx.x;
    const int tid = threadIdx.x;
    const int w = tid >> 6, l = tid & 63;
    const int l15 = l & 15, lg = l >> 4;

    // stage K and V^T (zero pad t >= 77)
    for (int c = tid; c < 768; c += 256) {
        const int t = c >> 3, dc = c & 7;
        union { uint4 u; u16 s[8]; } kv, vv;
        kv.u = make_uint4(0, 0, 0, 0);
        vv.u = make_uint4(0, 0, 0, 0);
        if (t < 77) {
            const long base = ((long)(b * 77 + t)) * 1024 + h * 64 + dc * 8;
            kv.u = *(const uint4*)&Kb[base];
            vv.u = *(const uint4*)&Vb[base];
        }
        *(uint4*)&Ks[t * 64 + dc * 8] = kv.u;
#pragma unroll
        for (int j = 0; j < 8; ++j) Vt[(dc * 8 + j) * 96 + t] = vv.s[j];
    }
    __syncthreads();

    // QK^T : rows w*32..+31, cols 0..95
    f32x4 acc[2][6] = {};
    const long qrow0 = (long)b * 4096 + nt * 128 + w * 32;
#pragma unroll
    for (int kk = 0; kk < 64; kk += 32) {
        bf16x8 a[2], kf[6];
#pragma unroll
        for (int m = 0; m < 2; ++m)
            a[m] = *(const bf16x8*)&Q[(qrow0 + m * 16 + l15) * 1024 + h * 64 + kk + lg * 8];
#pragma unroll
        for (int n = 0; n < 6; ++n)
            kf[n] = *(const bf16x8*)&Ks[(n * 16 + l15) * 64 + kk + lg * 8];
#pragma unroll
        for (int m = 0; m < 2; ++m)
#pragma unroll
            for (int n = 0; n < 6; ++n)
                acc[m][n] = __builtin_amdgcn_mfma_f32_16x16x32_bf16(
                    a[m], kf[n], acc[m][n], 0, 0, 0);
    }

    // softmax per row (each row lives in 16 lanes of one lg group), write P
    const float* mbase = mask + ((long)b * 4096 + nt * 128 + w * 32) * 77;
#pragma unroll
    for (int m = 0; m < 2; ++m) {
#pragma unroll
        for (int r = 0; r < 4; ++r) {
            const int row = m * 16 + lg * 4 + r;
            float vals[6];
            float rmax = -3e38f;
#pragma unroll
            for (int n = 0; n < 6; ++n) {
                const int col = n * 16 + l15;
                float v = -3e38f;
                if (col < 77) v = acc[m][n][r] * 0.125f + mbase[row * 77 + col];
                vals[n] = v;
                rmax = fmaxf(rmax, v);
            }
#pragma unroll
            for (int off = 1; off < 16; off <<= 1)
                rmax = fmaxf(rmax, __shfl_xor(rmax, off, 64));
            float s = 0.f;
#pragma unroll
            for (int n = 0; n < 6; ++n) {
                float e = (vals[n] > -1e37f) ? __expf(vals[n] - rmax) : 0.f;
                vals[n] = e;
                s += e;
            }
#pragma unroll
            for (int off = 1; off < 16; off <<= 1)
                s += __shfl_xor(s, off, 64);
            const float inv = 1.f / s;
#pragma unroll
            for (int n = 0; n < 6; ++n)
                Ps[(w * 32 + row) * 96 + n * 16 + l15] = f2bf(vals[n] * inv);
        }
    }
    __syncthreads();

    // PV : out[32 rows][64 cols] per wave, K = 96
    f32x4 o[2][4] = {};
#pragma unroll
    for (int kt = 0; kt < 96; kt += 32) {
        bf16x8 a[2], vf[4];
#pragma unroll
        for (int m = 0; m < 2; ++m)
            a[m] = *(const bf16x8*)&Ps[(w * 32 + m * 16 + l15) * 96 + kt + lg * 8];
#pragma unroll
        for (int n = 0; n < 4; ++n)
            vf[n] = *(const bf16x8*)&Vt[(n * 16 + l15) * 96 + kt + lg * 8];
#pragma unroll
        for (int m = 0; m < 2; ++m)
#pragma unroll
            for (int n = 0; n < 4; ++n)
                o[m][n] = __builtin_amdgcn_mfma_f32_16x16x32_bf16(
                    a[m], vf[n], o[m][n], 0, 0, 0);
    }

#pragma unroll
    for (int m = 0; m < 2; ++m)
#pragma unroll
        for (int n = 0; n < 4; ++n)
#pragma unroll
            for (int r = 0; r < 4; ++r) {
                const long row = (long)b * 4096 + nt * 128 + w * 32 + m * 16 + lg * 4 + r;
                const int col = h * 64 + n * 16 + l15;
                Ao[row * 1024 + col] = f2bf(o[m][n][r]);
            }
}

// ---------------- launch ----------------------------------------------------
extern "C" void kernel_launch(void* const* d_in, const int* in_sizes, int n_in,
                              void* d_out, int out_size, void* d_ws, size_t ws_size,
                              hipStream_t stream) {
    const float* hidden = (const float*)d_in[0];
    const float* enc = (const float*)d_in[1];
    const float* mask = (const float*)d_in[2];
    const float* Wq = (const float*)d_in[3];
    const float* bq = (const float*)d_in[4];
    const float* Wk = (const float*)d_in[5];
    const float* bk = (const float*)d_in[6];
    const float* Wv = (const float*)d_in[7];
    const float* bv = (const float*)d_in[8];
    const float* Wo = (const float*)d_in[9];
    const float* bo = (const float*)d_in[10];
    float* out = (float*)d_out;

    char* ws = (char*)d_ws;
    u16* hiddenB = (u16*)(ws);                       // 32 MB
    u16* Qb = (u16*)(ws + 33554432L);                // 32 MB
    u16* AoB = (u16*)(ws + 2 * 33554432L);           // 32 MB
    u16* WqB = (u16*)(ws + 3 * 33554432L);           // 2 MB
    u16* WkB = WqB + 1048576;
    u16* WvB = WkB + 1048576;
    u16* WoB = WvB + 1048576;
    u16* encB = WoB + 1048576;                       // 384*1024 bf16
    u16* Kbuf = encB + 393216;                       // 384*1024 bf16
    u16* Vbuf = Kbuf + 393216;

    auto cblocks = [](int n) { return dim3((unsigned)((n / 4 + 255) / 256)); };
    cvt_pad<<<cblocks(16777216), 256, 0, stream>>>(hidden, hiddenB, 16777216, 16777216);
    cvt_pad<<<cblocks(1048576), 256, 0, stream>>>(Wq, WqB, 1048576, 1048576);
    cvt_pad<<<cblocks(1048576), 256, 0, stream>>>(Wk, WkB, 1048576, 1048576);
    cvt_pad<<<cblocks(1048576), 256, 0, stream>>>(Wv, WvB, 1048576, 1048576);
    cvt_pad<<<cblocks(1048576), 256, 0, stream>>>(Wo, WoB, 1048576, 1048576);
    cvt_pad<<<cblocks(393216), 256, 0, stream>>>(enc, encB, 315392, 393216);

    gemm_bt<u16><<<dim3(8, 128), 256, 0, stream>>>(hiddenB, WqB, bq, Qb, 16384, 1024, 1024);
    gemm_bt<u16><<<dim3(8, 3), 256, 0, stream>>>(encB, WkB, bk, Kbuf, 384, 1024, 1024);
    gemm_bt<u16><<<dim3(8, 3), 256, 0, stream>>>(encB, WvB, bv, Vbuf, 384, 1024, 1024);

    attn_fused<<<dim3(32, 16, 4), 256, 0, stream>>>(Qb, Kbuf, Vbuf, mask, AoB);

    gemm_bt<float><<<dim3(8, 128), 256, 0, stream>>>(AoB, WoB, bo, out, 16384, 1024, 1024);
}

// Round 2
// 187.502 us; speedup vs baseline: 1.2148x; 1.2148x over previous
//
#include <hip/hip_runtime.h>
#include <cstdint>

typedef __bf16 bf16x8 __attribute__((ext_vector_type(8)));
typedef float f32x4 __attribute__((ext_vector_type(4)));
typedef unsigned short u16;
typedef unsigned int u32;

__device__ __forceinline__ u16 f2bf(float f) {
    u32 u = __builtin_bit_cast(u32, f);
    u += 0x7fffu + ((u >> 16) & 1u);
    return (u16)(u >> 16);
}

__device__ __forceinline__ void gl_lds16(const u16* g, u16* l) {
    __builtin_amdgcn_global_load_lds(
        (const __attribute__((address_space(1))) void*)g,
        (__attribute__((address_space(3))) void*)l,
        16, 0, 0);
}

__device__ __forceinline__ f32x4 mfma16(bf16x8 a, bf16x8 b, f32x4 c) {
    return __builtin_amdgcn_mfma_f32_16x16x32_bf16(a, b, c, 0, 0, 0);
}

// ---------------- fp32 -> bf16 conversions -------------------------------
__global__ void cvt_pad(const float* __restrict__ src, u16* __restrict__ dst,
                        int srcn, int totn) {
    int i = (blockIdx.x * 256 + threadIdx.x) * 4;
    if (i >= totn) return;
    float4 v = make_float4(0.f, 0.f, 0.f, 0.f);
    if (i < srcn) v = *(const float4*)&src[i];
    ushort4 o;
    o.x = f2bf(v.x); o.y = f2bf(v.y); o.z = f2bf(v.z); o.w = f2bf(v.w);
    *(ushort4*)&dst[i] = o;
}

struct CvtArgs {
    const float* s[5];
    u16* d[5];
    int srcn[5];
    int totn[5];
};

__global__ void cvt_multi(CvtArgs a) {
    const int seg = blockIdx.y;
    int i = (blockIdx.x * 256 + threadIdx.x) * 4;
    if (i >= a.totn[seg]) return;
    float4 v = make_float4(0.f, 0.f, 0.f, 0.f);
    if (i < a.srcn[seg]) v = *(const float4*)&a.s[seg][i];
    ushort4 o;
    o.x = f2bf(v.x); o.y = f2bf(v.y); o.z = f2bf(v.z); o.w = f2bf(v.w);
    *(ushort4*)&a.d[seg][i] = o;
}

// ---------------- big GEMM: 256x128 tile, BK=64, 3-deep pipeline ----------
// C[M,N] = A[M,K] @ W[N,K]^T + bias.  8 waves, per-wave 64x64 output.
// T2: XOR-chunk LDS swizzle (linear gl_lds dest + inverse-swz global src).
// T4: counted vmcnt(6) — stage tile t+2 while computing tile t.
// T1: bijective XCD swizzle on the (tn,tm) grid.
__device__ __forceinline__ void store_out(u16* C, long idx, float v) { C[idx] = f2bf(v); }
__device__ __forceinline__ void store_out(float* C, long idx, float v) { C[idx] = v; }

template <typename OutT>
__global__ __launch_bounds__(512, 2) void gemm256(
    const u16* __restrict__ A, const u16* __restrict__ W,
    const float* __restrict__ bias, OutT* __restrict__ C,
    int M, int N, int K) {
    __shared__ __align__(16) u16 As[3][256 * 64];
    __shared__ __align__(16) u16 Bs[3][128 * 64];

    const int tid = threadIdx.x;
    const int wid = tid >> 6, l = tid & 63;
    const int wr = wid >> 1, wc = wid & 1;    // wave -> (m 0..3, n 0..1)
    const int l15 = l & 15, lg = l >> 4;

    // XCD-aware bijective swizzle (nwg % 8 == 0 guaranteed by grid choice)
    const int nwg = gridDim.x * gridDim.y;
    const int lin = blockIdx.y * gridDim.x + blockIdx.x;
    const int cpx = nwg >> 3;
    const int swz = (lin & 7) * cpx + (lin >> 3);
    const long tn = swz % gridDim.x;
    const long tm = swz / gridDim.x;

    const u16* Ab = A + tm * 256 * (long)K;
    const u16* Bb = W + tn * 128 * (long)K;

    // staging addressing: issue j covers rows j*64..j*64+63 (8 KB each)
    const int srow = tid >> 3;                 // row within 64-row block
    const int schunk = tid & 7;                // 16B chunk within 128B row
    const int swch = schunk ^ (srow & 7);      // inverse-swizzled source chunk
    const long asrc = (long)srow * K + swch * 8;

    const int NT = K >> 6;

#define STAGE(bufi, k0)                                                        \
    do {                                                                       \
        u16* ab_ = &As[bufi][0];                                               \
        u16* bb_ = &Bs[bufi][0];                                               \
        _Pragma("unroll")                                                      \
        for (int j_ = 0; j_ < 4; ++j_)                                         \
            gl_lds16(Ab + (long)(j_ * 64) * K + asrc + (k0),                   \
                     ab_ + j_ * 4096 + tid * 8);                               \
        _Pragma("unroll")                                                      \
        for (int j_ = 0; j_ < 2; ++j_)                                         \
            gl_lds16(Bb + (long)(j_ * 64) * K + asrc + (k0),                   \
                     bb_ + j_ * 4096 + tid * 8);                               \
    } while (0)

    f32x4 acc[4][4] = {};

    STAGE(0, 0);
    STAGE(1, 64);

    const int rchunk = lg;              // chunk within 64B k-half
    const int rsw = l15 & 7;            // row&7 for swizzled read

    for (int t = 0; t < NT; ++t) {
        if (t + 1 < NT) {
            asm volatile("s_waitcnt vmcnt(6)" ::: "memory");
        } else {
            asm volatile("s_waitcnt vmcnt(0)" ::: "memory");
        }
        __builtin_amdgcn_sched_barrier(0);
        __builtin_amdgcn_s_barrier();

        const int buf = t % 3;
        if (t + 2 < NT) {
            const int nb = (t + 2) % 3;
            STAGE(nb, (t + 2) << 6);
        }

        bf16x8 a[4][2], b[4][2];
#pragma unroll
        for (int m = 0; m < 4; ++m) {
            const int row = wr * 64 + m * 16 + l15;
#pragma unroll
            for (int kk = 0; kk < 2; ++kk) {
                const int c = (kk * 4 + rchunk) ^ rsw;
                a[m][kk] = *(const bf16x8*)&As[buf][row * 64 + c * 8];
            }
        }
#pragma unroll
        for (int n = 0; n < 4; ++n) {
            const int row = wc * 64 + n * 16 + l15;
#pragma unroll
            for (int kk = 0; kk < 2; ++kk) {
                const int c = (kk * 4 + rchunk) ^ rsw;
                b[n][kk] = *(const bf16x8*)&Bs[buf][row * 64 + c * 8];
            }
        }

        __builtin_amdgcn_s_setprio(1);
#pragma unroll
        for (int m = 0; m < 4; ++m)
#pragma unroll
            for (int n = 0; n < 4; ++n) {
                acc[m][n] = mfma16(a[m][0], b[n][0], acc[m][n]);
                acc[m][n] = mfma16(a[m][1], b[n][1], acc[m][n]);
            }
        __builtin_amdgcn_s_setprio(0);
    }
#undef STAGE

    const long row0 = tm * 256 + wr * 64;
    const long col0 = tn * 128 + wc * 64;
#pragma unroll
    for (int m = 0; m < 4; ++m)
#pragma unroll
        for (int n = 0; n < 4; ++n)
#pragma unroll
            for (int r = 0; r < 4; ++r) {
                const long row = row0 + m * 16 + lg * 4 + r;
                const long col = col0 + n * 16 + l15;
                store_out(C, row * N + col, acc[m][n][r] + bias[col]);
            }
}

// ---------------- small GEMM for K/V projections (m97 128-tile) -----------
__device__ __forceinline__ void gemm128_body(
    const u16* __restrict__ A, const u16* __restrict__ W,
    const float* __restrict__ bias, u16* __restrict__ C,
    int N, int K) {
    __shared__ u16 As[128 * 64];
    __shared__ u16 Bs[128 * 64];
    const int tid = threadIdx.x;
    const int w = tid >> 6, l = tid & 63;
    const int wr = w >> 1, wc = w & 1;
    const int l15 = l & 15, lg = l >> 4;
    const long tm = blockIdx.y, tn = blockIdx.x;
    const u16* Ab = A + tm * 128 * (long)K;
    const u16* Bb = W + tn * 128 * (long)K;

    f32x4 acc[4][4] = {};

    for (int k0 = 0; k0 < K; k0 += 64) {
#pragma unroll
        for (int t = 0; t < 4; ++t) {
            int i = t * 256 + tid;
            int row = i >> 3, cc = i & 7;
            gl_lds16(Ab + (long)row * K + k0 + cc * 8, &As[i * 8]);
            gl_lds16(Bb + (long)row * K + k0 + cc * 8, &Bs[i * 8]);
        }
        __syncthreads();
#pragma unroll
        for (int kk = 0; kk < 64; kk += 32) {
            bf16x8 a[4], b[4];
#pragma unroll
            for (int m = 0; m < 4; ++m)
                a[m] = *(const bf16x8*)&As[(wr * 64 + m * 16 + l15) * 64 + kk + lg * 8];
#pragma unroll
            for (int n = 0; n < 4; ++n)
                b[n] = *(const bf16x8*)&Bs[(wc * 64 + n * 16 + l15) * 64 + kk + lg * 8];
#pragma unroll
            for (int m = 0; m < 4; ++m)
#pragma unroll
                for (int n = 0; n < 4; ++n)
                    acc[m][n] = mfma16(a[m], b[n], acc[m][n]);
        }
        __syncthreads();
    }

    const long row0 = tm * 128 + wr * 64;
    const long col0 = tn * 128 + wc * 64;
#pragma unroll
    for (int m = 0; m < 4; ++m)
#pragma unroll
        for (int n = 0; n < 4; ++n)
#pragma unroll
            for (int r = 0; r < 4; ++r) {
                const long row = row0 + m * 16 + lg * 4 + r;
                const long col = col0 + n * 16 + l15;
                C[row * N + col] = f2bf(acc[m][n][r] + bias[col]);
            }
}

__global__ __launch_bounds__(256) void gemm_kv(
    const u16* __restrict__ A,
    const u16* __restrict__ Wk, const float* __restrict__ bk, u16* __restrict__ Ko,
    const u16* __restrict__ Wv, const float* __restrict__ bv, u16* __restrict__ Vo,
    int N, int K) {
    const bool isv = blockIdx.z != 0;
    gemm128_body(A, isv ? Wv : Wk, isv ? bv : bk, isv ? Vo : Ko, N, K);
}

// ---------------- fused attention ------------------------------------------
__global__ __launch_bounds__(256) void attn_fused(
    const u16* __restrict__ Q,   // [B*4096, 1024] bf16
    const u16* __restrict__ Kb,  // [B*77 (pad 384), 1024] bf16
    const u16* __restrict__ Vb,
    const float* __restrict__ mask,  // [B, 4096, 77] f32
    u16* __restrict__ Ao) {
    __shared__ u16 Ks[96 * 64];
    __shared__ u16 Vt[64 * 96];
    __shared__ u16 Ps[128 * 96];

    const int b = blockIdx.z, h = blockIdx.y, nt = blockIdx.x;
    const int tid = threadIdx.x;
    const int w = tid >> 6, l = tid & 63;
    const int l15 = l & 15, lg = l >> 4;

    for (int c = tid; c < 768; c += 256) {
        const int t = c >> 3, dc = c & 7;
        union { uint4 u; u16 s[8]; } kv, vv;
        kv.u = make_uint4(0, 0, 0, 0);
        vv.u = make_uint4(0, 0, 0, 0);
        if (t < 77) {
            const long base = ((long)(b * 77 + t)) * 1024 + h * 64 + dc * 8;
            kv.u = *(const uint4*)&Kb[base];
            vv.u = *(const uint4*)&Vb[base];
        }
        *(uint4*)&Ks[t * 64 + dc * 8] = kv.u;
#pragma unroll
        for (int j = 0; j < 8; ++j) Vt[(dc * 8 + j) * 96 + t] = vv.s[j];
    }
    __syncthreads();

    f32x4 acc[2][6] = {};
    const long qrow0 = (long)b * 4096 + nt * 128 + w * 32;
#pragma unroll
    for (int kk = 0; kk < 64; kk += 32) {
        bf16x8 a[2], kf[6];
#pragma unroll
        for (int m = 0; m < 2; ++m)
            a[m] = *(const bf16x8*)&Q[(qrow0 + m * 16 + l15) * 1024 + h * 64 + kk + lg * 8];
#pragma unroll
        for (int n = 0; n < 6; ++n)
            kf[n] = *(const bf16x8*)&Ks[(n * 16 + l15) * 64 + kk + lg * 8];
#pragma unroll
        for (int m = 0; m < 2; ++m)
#pragma unroll
            for (int n = 0; n < 6; ++n)
                acc[m][n] = mfma16(a[m], kf[n], acc[m][n]);
    }

    const float* mbase = mask + ((long)b * 4096 + nt * 128 + w * 32) * 77;
#pragma unroll
    for (int m = 0; m < 2; ++m) {
#pragma unroll
        for (int r = 0; r < 4; ++r) {
            const int row = m * 16 + lg * 4 + r;
            float vals[6];
            float rmax = -3e38f;
#pragma unroll
            for (int n = 0; n < 6; ++n) {
                const int col = n * 16 + l15;
                float v = -3e38f;
                if (col < 77) v = acc[m][n][r] * 0.125f + mbase[row * 77 + col];
                vals[n] = v;
                rmax = fmaxf(rmax, v);
            }
#pragma unroll
            for (int off = 1; off < 16; off <<= 1)
                rmax = fmaxf(rmax, __shfl_xor(rmax, off, 64));
            float s = 0.f;
#pragma unroll
            for (int n = 0; n < 6; ++n) {
                float e = (vals[n] > -1e37f) ? __expf(vals[n] - rmax) : 0.f;
                vals[n] = e;
                s += e;
            }
#pragma unroll
            for (int off = 1; off < 16; off <<= 1)
                s += __shfl_xor(s, off, 64);
            const float inv = 1.f / s;
#pragma unroll
            for (int n = 0; n < 6; ++n)
                Ps[(w * 32 + row) * 96 + n * 16 + l15] = f2bf(vals[n] * inv);
        }
    }
    __syncthreads();

    f32x4 o[2][4] = {};
#pragma unroll
    for (int kt = 0; kt < 96; kt += 32) {
        bf16x8 a[2], vf[4];
#pragma unroll
        for (int m = 0; m < 2; ++m)
            a[m] = *(const bf16x8*)&Ps[(w * 32 + m * 16 + l15) * 96 + kt + lg * 8];
#pragma unroll
        for (int n = 0; n < 4; ++n)
            vf[n] = *(const bf16x8*)&Vt[(n * 16 + l15) * 96 + kt + lg * 8];
#pragma unroll
        for (int m = 0; m < 2; ++m)
#pragma unroll
            for (int n = 0; n < 4; ++n)
                o[m][n] = mfma16(a[m], vf[n], o[m][n]);
    }

#pragma unroll
    for (int m = 0; m < 2; ++m)
#pragma unroll
        for (int n = 0; n < 4; ++n)
#pragma unroll
            for (int r = 0; r < 4; ++r) {
                const long row = (long)b * 4096 + nt * 128 + w * 32 + m * 16 + lg * 4 + r;
                const int col = h * 64 + n * 16 + l15;
                Ao[row * 1024 + col] = f2bf(o[m][n][r]);
            }
}

// ---------------- launch ----------------------------------------------------
extern "C" void kernel_launch(void* const* d_in, const int* in_sizes, int n_in,
                              void* d_out, int out_size, void* d_ws, size_t ws_size,
                              hipStream_t stream) {
    const float* hidden = (const float*)d_in[0];
    const float* enc = (const float*)d_in[1];
    const float* mask = (const float*)d_in[2];
    const float* Wq = (const float*)d_in[3];
    const float* bq = (const float*)d_in[4];
    const float* Wk = (const float*)d_in[5];
    const float* bk = (const float*)d_in[6];
    const float* Wv = (const float*)d_in[7];
    const float* bv = (const float*)d_in[8];
    const float* Wo = (const float*)d_in[9];
    const float* bo = (const float*)d_in[10];
    float* out = (float*)d_out;

    char* ws = (char*)d_ws;
    u16* hiddenB = (u16*)(ws);                       // 32 MB
    u16* Qb = (u16*)(ws + 33554432L);                // 32 MB
    u16* AoB = (u16*)(ws + 2 * 33554432L);           // 32 MB
    u16* WqB = (u16*)(ws + 3 * 33554432L);           // 2 MB each
    u16* WkB = WqB + 1048576;
    u16* WvB = WkB + 1048576;
    u16* WoB = WvB + 1048576;
    u16* encB = WoB + 1048576;                       // 384*1024 bf16
    u16* Kbuf = encB + 393216;
    u16* Vbuf = Kbuf + 393216;

    // conversions: hidden (big) + {4 weights, enc} in one multi-segment kernel
    cvt_pad<<<dim3(16384), 256, 0, stream>>>(hidden, hiddenB, 16777216, 16777216);
    CvtArgs ca;
    ca.s[0] = Wq;  ca.d[0] = WqB; ca.srcn[0] = 1048576; ca.totn[0] = 1048576;
    ca.s[1] = Wk;  ca.d[1] = WkB; ca.srcn[1] = 1048576; ca.totn[1] = 1048576;
    ca.s[2] = Wv;  ca.d[2] = WvB; ca.srcn[2] = 1048576; ca.totn[2] = 1048576;
    ca.s[3] = Wo;  ca.d[3] = WoB; ca.srcn[3] = 1048576; ca.totn[3] = 1048576;
    ca.s[4] = enc; ca.d[4] = encB; ca.srcn[4] = 315392; ca.totn[4] = 393216;
    cvt_multi<<<dim3(1024, 5), 256, 0, stream>>>(ca);

    // projections
    gemm256<u16><<<dim3(8, 64), 512, 0, stream>>>(hiddenB, WqB, bq, Qb, 16384, 1024, 1024);
    gemm_kv<<<dim3(8, 3, 2), 256, 0, stream>>>(encB, WkB, bk, Kbuf, WvB, bv, Vbuf, 1024, 1024);

    attn_fused<<<dim3(32, 16, 4), 256, 0, stream>>>(Qb, Kbuf, Vbuf, mask, AoB);

    gemm256<float><<<dim3(8, 64), 512, 0, stream>>>(AoB, WoB, bo, out, 16384, 1024, 1024);
}

// Round 3
// 171.847 us; speedup vs baseline: 1.3255x; 1.0911x over previous
//
#include <hip/hip_runtime.h>
#include <cstdint>

typedef __bf16 bf16x8 __attribute__((ext_vector_type(8)));
typedef float f32x4 __attribute__((ext_vector_type(4)));
typedef unsigned short u16;
typedef unsigned int u32;

__device__ __forceinline__ u16 f2bf(float f) {
    u32 u = __builtin_bit_cast(u32, f);
    u += 0x7fffu + ((u >> 16) & 1u);
    return (u16)(u >> 16);
}

__device__ __forceinline__ void gl_lds16(const u16* g, u16* l) {
    __builtin_amdgcn_global_load_lds(
        (const __attribute__((address_space(1))) void*)g,
        (__attribute__((address_space(3))) void*)l,
        16, 0, 0);
}

__device__ __forceinline__ f32x4 mfma16(bf16x8 a, bf16x8 b, f32x4 c) {
    return __builtin_amdgcn_mfma_f32_16x16x32_bf16(a, b, c, 0, 0, 0);
}

// ---------------- fp32 -> bf16 conversions -------------------------------
__global__ void cvt_pad(const float* __restrict__ src, u16* __restrict__ dst,
                        int srcn, int totn) {
    int i = (blockIdx.x * 256 + threadIdx.x) * 4;
    if (i >= totn) return;
    float4 v = make_float4(0.f, 0.f, 0.f, 0.f);
    if (i < srcn) v = *(const float4*)&src[i];
    ushort4 o;
    o.x = f2bf(v.x); o.y = f2bf(v.y); o.z = f2bf(v.z); o.w = f2bf(v.w);
    *(ushort4*)&dst[i] = o;
}

struct CvtArgs {
    const float* s[5];
    u16* d[5];
    int srcn[5];
    int totn[5];
};

__global__ void cvt_multi(CvtArgs a) {
    const int seg = blockIdx.y;
    int i = (blockIdx.x * 256 + threadIdx.x) * 4;
    if (i >= a.totn[seg]) return;
    float4 v = make_float4(0.f, 0.f, 0.f, 0.f);
    if (i < a.srcn[seg]) v = *(const float4*)&a.s[seg][i];
    ushort4 o;
    o.x = f2bf(v.x); o.y = f2bf(v.y); o.z = f2bf(v.z); o.w = f2bf(v.w);
    *(ushort4*)&a.d[seg][i] = o;
}

// ---------------- big GEMM: 256x256 tile, BK=32, 4-slot ring, 8-phase -----
// C[M,N] = A[M,K] @ W[N,K]^T + bias. 8 waves (2 M-rows x 4 N-cols), each
// wave computes 128x64. Two phases per K-tile; counted vmcnt(4) per K-tile.
__device__ __forceinline__ void store_out(u16* C, long idx, float v) { C[idx] = f2bf(v); }
__device__ __forceinline__ void store_out(float* C, long idx, float v) { C[idx] = v; }

template <typename OutT>
__global__ __launch_bounds__(512, 2) void gemm8p(
    const u16* __restrict__ A, const u16* __restrict__ W,
    const float* __restrict__ bias, OutT* __restrict__ C,
    int M, int N, int K) {
    __shared__ __align__(16) u16 As[4][256 * 32];  // 4 slots x 16KB
    __shared__ __align__(16) u16 Bs[4][256 * 32];

    const int tid = threadIdx.x;
    const int wid = tid >> 6, l = tid & 63;
    const int wr = wid >> 2, wc = wid & 3;      // wave -> (M-half, N-quarter)
    const int l15 = l & 15, lg = l >> 4;

    // XCD-aware bijective swizzle (nwg = 256, % 8 == 0)
    const int lin = blockIdx.y * gridDim.x + blockIdx.x;
    const int cpx = (gridDim.x * gridDim.y) >> 3;
    const int swz = (lin & 7) * cpx + (lin >> 3);
    const long tn = swz % gridDim.x;
    const long tm = swz / gridDim.x;

    const u16* Ab = A + tm * 256 * (long)K;
    const u16* Bb = W + tn * 256 * (long)K;

    // staging addressing: one issue = 512 thr x 16B = 128 rows x 32 cols
    const int srow = tid >> 2;                                  // 0..127
    const int sch = (tid & 3) ^ (srow & 3) ^ ((srow >> 2) & 3); // pre-swizzled src chunk
    const long asrc = (long)srow * K + sch * 8;

    // swizzled read chunk (byte offset/2): lane-constant
    const int rch = (lg ^ (l15 & 3) ^ ((l15 >> 2) & 3)) * 8;

    const int NT = K >> 5;  // 32 K-tiles of 32

#define STAGE_A(ss, t_)                                                       \
    do {                                                                      \
        u16* p_ = &As[ss][0];                                                 \
        gl_lds16(Ab + asrc + (long)(t_)*32, p_ + tid * 8);                    \
        gl_lds16(Ab + 128L * K + asrc + (long)(t_)*32, p_ + 4096 + tid * 8);  \
    } while (0)
#define STAGE_B(ss, t_)                                                       \
    do {                                                                      \
        u16* p_ = &Bs[ss][0];                                                 \
        gl_lds16(Bb + asrc + (long)(t_)*32, p_ + tid * 8);                    \
        gl_lds16(Bb + 128L * K + asrc + (long)(t_)*32, p_ + 4096 + tid * 8);  \
    } while (0)

    f32x4 acc[8][4] = {};

    // prologue: stage K-tiles 0,1 ; wait for tile 0 ; barrier
    STAGE_A(0, 0); STAGE_B(0, 0);
    STAGE_A(1, 1); STAGE_B(1, 1);
    asm volatile("s_waitcnt vmcnt(4)" ::: "memory");
    __builtin_amdgcn_sched_barrier(0);
    __builtin_amdgcn_s_barrier();

    for (int t0 = 0; t0 < NT; t0 += 4) {
#pragma unroll
        for (int u = 0; u < 4; ++u) {
            const int t = t0 + u;
            const int slot = u;            // t & 3
            const int ss = (u + 2) & 3;
            const bool st = (t + 2) < NT;

            bf16x8 a[4], b[4];
            // ---- phase 1: lower M-half quadrant ----
#pragma unroll
            for (int mf = 0; mf < 4; ++mf)
                a[mf] = *(const bf16x8*)&As[slot][(wr * 128 + mf * 16 + l15) * 32 + rch];
#pragma unroll
            for (int nf = 0; nf < 4; ++nf)
                b[nf] = *(const bf16x8*)&Bs[slot][(wc * 64 + nf * 16 + l15) * 32 + rch];
            if (st) STAGE_A(ss, t + 2);
            __builtin_amdgcn_s_barrier();
            asm volatile("s_waitcnt lgkmcnt(0)" ::: "memory");
            __builtin_amdgcn_sched_barrier(0);
            __builtin_amdgcn_s_setprio(1);
#pragma unroll
            for (int mf = 0; mf < 4; ++mf)
#pragma unroll
                for (int nf = 0; nf < 4; ++nf)
                    acc[mf][nf] = mfma16(a[mf], b[nf], acc[mf][nf]);
            __builtin_amdgcn_s_setprio(0);
            __builtin_amdgcn_s_barrier();

            // ---- phase 2: upper M-half quadrant ----
            bf16x8 a2[4];
#pragma unroll
            for (int mf = 0; mf < 4; ++mf)
                a2[mf] = *(const bf16x8*)&As[slot][(wr * 128 + (mf + 4) * 16 + l15) * 32 + rch];
            if (st) STAGE_B(ss, t + 2);
            __builtin_amdgcn_s_barrier();
            asm volatile("s_waitcnt lgkmcnt(0)" ::: "memory");
            __builtin_amdgcn_sched_barrier(0);
            __builtin_amdgcn_s_setprio(1);
#pragma unroll
            for (int mf = 0; mf < 4; ++mf)
#pragma unroll
                for (int nf = 0; nf < 4; ++nf)
                    acc[mf + 4][nf] = mfma16(a2[mf], b[nf], acc[mf + 4][nf]);
            __builtin_amdgcn_s_setprio(0);
            if (st)
                asm volatile("s_waitcnt vmcnt(4)" ::: "memory");
            else
                asm volatile("s_waitcnt vmcnt(0)" ::: "memory");
            __builtin_amdgcn_sched_barrier(0);
            __builtin_amdgcn_s_barrier();
        }
    }
#undef STAGE_A
#undef STAGE_B

    const long row0 = tm * 256 + wr * 128;
    const long col0 = tn * 256 + wc * 64;
    float bv[4];
#pragma unroll
    for (int nf = 0; nf < 4; ++nf) bv[nf] = bias[col0 + nf * 16 + l15];
#pragma unroll
    for (int mf = 0; mf < 8; ++mf)
#pragma unroll
        for (int nf = 0; nf < 4; ++nf)
#pragma unroll
            for (int r = 0; r < 4; ++r) {
                const long row = row0 + mf * 16 + lg * 4 + r;
                const long col = col0 + nf * 16 + l15;
                store_out(C, row * N + col, acc[mf][nf][r] + bv[nf]);
            }
}

// ---------------- small GEMM for K/V projections (m97 128-tile) -----------
__device__ __forceinline__ void gemm128_body(
    const u16* __restrict__ A, const u16* __restrict__ W,
    const float* __restrict__ bias, u16* __restrict__ C,
    int N, int K) {
    __shared__ u16 As[128 * 64];
    __shared__ u16 Bs[128 * 64];
    const int tid = threadIdx.x;
    const int w = tid >> 6, l = tid & 63;
    const int wr = w >> 1, wc = w & 1;
    const int l15 = l & 15, lg = l >> 4;
    const long tm = blockIdx.y, tn = blockIdx.x;
    const u16* Ab = A + tm * 128 * (long)K;
    const u16* Bb = W + tn * 128 * (long)K;

    f32x4 acc[4][4] = {};

    for (int k0 = 0; k0 < K; k0 += 64) {
#pragma unroll
        for (int t = 0; t < 4; ++t) {
            int i = t * 256 + tid;
            int row = i >> 3, cc = i & 7;
            gl_lds16(Ab + (long)row * K + k0 + cc * 8, &As[i * 8]);
            gl_lds16(Bb + (long)row * K + k0 + cc * 8, &Bs[i * 8]);
        }
        __syncthreads();
#pragma unroll
        for (int kk = 0; kk < 64; kk += 32) {
            bf16x8 a[4], b[4];
#pragma unroll
            for (int m = 0; m < 4; ++m)
                a[m] = *(const bf16x8*)&As[(wr * 64 + m * 16 + l15) * 64 + kk + lg * 8];
#pragma unroll
            for (int n = 0; n < 4; ++n)
                b[n] = *(const bf16x8*)&Bs[(wc * 64 + n * 16 + l15) * 64 + kk + lg * 8];
#pragma unroll
            for (int m = 0; m < 4; ++m)
#pragma unroll
                for (int n = 0; n < 4; ++n)
                    acc[m][n] = mfma16(a[m], b[n], acc[m][n]);
        }
        __syncthreads();
    }

    const long row0 = tm * 128 + wr * 64;
    const long col0 = tn * 128 + wc * 64;
#pragma unroll
    for (int m = 0; m < 4; ++m)
#pragma unroll
        for (int n = 0; n < 4; ++n)
#pragma unroll
            for (int r = 0; r < 4; ++r) {
                const long row = row0 + m * 16 + lg * 4 + r;
                const long col = col0 + n * 16 + l15;
                C[row * N + col] = f2bf(acc[m][n][r] + bias[col]);
            }
}

__global__ __launch_bounds__(256) void gemm_kv(
    const u16* __restrict__ A,
    const u16* __restrict__ Wk, const float* __restrict__ bk, u16* __restrict__ Ko,
    const u16* __restrict__ Wv, const float* __restrict__ bv, u16* __restrict__ Vo,
    int N, int K) {
    const bool isv = blockIdx.z != 0;
    gemm128_body(A, isv ? Wv : Wk, isv ? bv : bk, isv ? Vo : Ko, N, K);
}

// ---------------- fused attention ------------------------------------------
__global__ __launch_bounds__(256) void attn_fused(
    const u16* __restrict__ Q,   // [B*4096, 1024] bf16
    const u16* __restrict__ Kb,  // [B*77 (pad 384), 1024] bf16
    const u16* __restrict__ Vb,
    const float* __restrict__ mask,  // [B, 4096, 77] f32
    u16* __restrict__ Ao) {
    __shared__ u16 Ks[96 * 64];
    __shared__ u16 Vt[64 * 96];
    __shared__ u16 Ps[128 * 96];

    const int b = blockIdx.z, h = blockIdx.y, nt = blockIdx.x;
    const int tid = threadIdx.x;
    const int w = tid >> 6, l = tid & 63;
    const int l15 = l & 15, lg = l >> 4;

    for (int c = tid; c < 768; c += 256) {
        const int t = c >> 3, dc = c & 7;
        union { uint4 u; u16 s[8]; } kv, vv;
        kv.u = make_uint4(0, 0, 0, 0);
        vv.u = make_uint4(0, 0, 0, 0);
        if (t < 77) {
            const long base = ((long)(b * 77 + t)) * 1024 + h * 64 + dc * 8;
            kv.u = *(const uint4*)&Kb[base];
            vv.u = *(const uint4*)&Vb[base];
        }
        *(uint4*)&Ks[t * 64 + dc * 8] = kv.u;
#pragma unroll
        for (int j = 0; j < 8; ++j) Vt[(dc * 8 + j) * 96 + t] = vv.s[j];
    }
    __syncthreads();

    f32x4 acc[2][6] = {};
    const long qrow0 = (long)b * 4096 + nt * 128 + w * 32;
#pragma unroll
    for (int kk = 0; kk < 64; kk += 32) {
        bf16x8 a[2], kf[6];
#pragma unroll
        for (int m = 0; m < 2; ++m)
            a[m] = *(const bf16x8*)&Q[(qrow0 + m * 16 + l15) * 1024 + h * 64 + kk + lg * 8];
#pragma unroll
        for (int n = 0; n < 6; ++n)
            kf[n] = *(const bf16x8*)&Ks[(n * 16 + l15) * 64 + kk + lg * 8];
#pragma unroll
        for (int m = 0; m < 2; ++m)
#pragma unroll
            for (int n = 0; n < 6; ++n)
                acc[m][n] = mfma16(a[m], kf[n], acc[m][n]);
    }

    const float* mbase = mask + ((long)b * 4096 + nt * 128 + w * 32) * 77;
#pragma unroll
    for (int m = 0; m < 2; ++m) {
#pragma unroll
        for (int r = 0; r < 4; ++r) {
            const int row = m * 16 + lg * 4 + r;
            float vals[6];
            float rmax = -3e38f;
#pragma unroll
            for (int n = 0; n < 6; ++n) {
                const int col = n * 16 + l15;
                float v = -3e38f;
                if (col < 77) v = acc[m][n][r] * 0.125f + mbase[row * 77 + col];
                vals[n] = v;
                rmax = fmaxf(rmax, v);
            }
#pragma unroll
            for (int off = 1; off < 16; off <<= 1)
                rmax = fmaxf(rmax, __shfl_xor(rmax, off, 64));
            float s = 0.f;
#pragma unroll
            for (int n = 0; n < 6; ++n) {
                float e = (vals[n] > -1e37f) ? __expf(vals[n] - rmax) : 0.f;
                vals[n] = e;
                s += e;
            }
#pragma unroll
            for (int off = 1; off < 16; off <<= 1)
                s += __shfl_xor(s, off, 64);
            const float inv = 1.f / s;
#pragma unroll
            for (int n = 0; n < 6; ++n)
                Ps[(w * 32 + row) * 96 + n * 16 + l15] = f2bf(vals[n] * inv);
        }
    }
    __syncthreads();

    f32x4 o[2][4] = {};
#pragma unroll
    for (int kt = 0; kt < 96; kt += 32) {
        bf16x8 a[2], vf[4];
#pragma unroll
        for (int m = 0; m < 2; ++m)
            a[m] = *(const bf16x8*)&Ps[(w * 32 + m * 16 + l15) * 96 + kt + lg * 8];
#pragma unroll
        for (int n = 0; n < 4; ++n)
            vf[n] = *(const bf16x8*)&Vt[(n * 16 + l15) * 96 + kt + lg * 8];
#pragma unroll
        for (int m = 0; m < 2; ++m)
#pragma unroll
            for (int n = 0; n < 4; ++n)
                o[m][n] = mfma16(a[m], vf[n], o[m][n]);
    }

#pragma unroll
    for (int m = 0; m < 2; ++m)
#pragma unroll
        for (int n = 0; n < 4; ++n)
#pragma unroll
            for (int r = 0; r < 4; ++r) {
                const long row = (long)b * 4096 + nt * 128 + w * 32 + m * 16 + lg * 4 + r;
                const int col = h * 64 + n * 16 + l15;
                Ao[row * 1024 + col] = f2bf(o[m][n][r]);
            }
}

// ---------------- launch ----------------------------------------------------
extern "C" void kernel_launch(void* const* d_in, const int* in_sizes, int n_in,
                              void* d_out, int out_size, void* d_ws, size_t ws_size,
                              hipStream_t stream) {
    const float* hidden = (const float*)d_in[0];
    const float* enc = (const float*)d_in[1];
    const float* mask = (const float*)d_in[2];
    const float* Wq = (const float*)d_in[3];
    const float* bq = (const float*)d_in[4];
    const float* Wk = (const float*)d_in[5];
    const float* bk = (const float*)d_in[6];
    const float* Wv = (const float*)d_in[7];
    const float* bv = (const float*)d_in[8];
    const float* Wo = (const float*)d_in[9];
    const float* bo = (const float*)d_in[10];
    float* out = (float*)d_out;

    char* ws = (char*)d_ws;
    u16* hiddenB = (u16*)(ws);                       // 32 MB
    u16* Qb = (u16*)(ws + 33554432L);                // 32 MB
    u16* AoB = (u16*)(ws + 2 * 33554432L);           // 32 MB
    u16* WqB = (u16*)(ws + 3 * 33554432L);           // 2 MB each
    u16* WkB = WqB + 1048576;
    u16* WvB = WkB + 1048576;
    u16* WoB = WvB + 1048576;
    u16* encB = WoB + 1048576;                       // 384*1024 bf16
    u16* Kbuf = encB + 393216;
    u16* Vbuf = Kbuf + 393216;

    cvt_pad<<<dim3(16384), 256, 0, stream>>>(hidden, hiddenB, 16777216, 16777216);
    CvtArgs ca;
    ca.s[0] = Wq;  ca.d[0] = WqB; ca.srcn[0] = 1048576; ca.totn[0] = 1048576;
    ca.s[1] = Wk;  ca.d[1] = WkB; ca.srcn[1] = 1048576; ca.totn[1] = 1048576;
    ca.s[2] = Wv;  ca.d[2] = WvB; ca.srcn[2] = 1048576; ca.totn[2] = 1048576;
    ca.s[3] = Wo;  ca.d[3] = WoB; ca.srcn[3] = 1048576; ca.totn[3] = 1048576;
    ca.s[4] = enc; ca.d[4] = encB; ca.srcn[4] = 315392; ca.totn[4] = 393216;
    cvt_multi<<<dim3(1024, 5), 256, 0, stream>>>(ca);

    // projections
    gemm8p<u16><<<dim3(4, 64), 512, 0, stream>>>(hiddenB, WqB, bq, Qb, 16384, 1024, 1024);
    gemm_kv<<<dim3(8, 3, 2), 256, 0, stream>>>(encB, WkB, bk, Kbuf, WvB, bv, Vbuf, 1024, 1024);

    attn_fused<<<dim3(32, 16, 4), 256, 0, stream>>>(Qb, Kbuf, Vbuf, mask, AoB);

    gemm8p<float><<<dim3(4, 64), 512, 0, stream>>>(AoB, WoB, bo, out, 16384, 1024, 1024);
}

// Round 4
// 163.323 us; speedup vs baseline: 1.3946x; 1.0522x over previous
//
#include <hip/hip_runtime.h>
#include <cstdint>

typedef __bf16 bf16x8 __attribute__((ext_vector_type(8)));
typedef float f32x4 __attribute__((ext_vector_type(4)));
typedef unsigned short u16;
typedef unsigned int u32;

__device__ __forceinline__ u16 f2bf(float f) {
    u32 u = __builtin_bit_cast(u32, f);
    u += 0x7fffu + ((u >> 16) & 1u);
    return (u16)(u >> 16);
}

__device__ __forceinline__ void gl_lds16(const u16* g, u16* l) {
    __builtin_amdgcn_global_load_lds(
        (const __attribute__((address_space(1))) void*)g,
        (__attribute__((address_space(3))) void*)l,
        16, 0, 0);
}

__device__ __forceinline__ f32x4 mfma16(bf16x8 a, bf16x8 b, f32x4 c) {
    return __builtin_amdgcn_mfma_f32_16x16x32_bf16(a, b, c, 0, 0, 0);
}

// ---------------- fp32 -> bf16 conversions -------------------------------
__global__ void cvt_pad(const float* __restrict__ src, u16* __restrict__ dst,
                        int srcn, int totn) {
    int i = (blockIdx.x * 256 + threadIdx.x) * 4;
    if (i >= totn) return;
    float4 v = make_float4(0.f, 0.f, 0.f, 0.f);
    if (i < srcn) v = *(const float4*)&src[i];
    ushort4 o;
    o.x = f2bf(v.x); o.y = f2bf(v.y); o.z = f2bf(v.z); o.w = f2bf(v.w);
    *(ushort4*)&dst[i] = o;
}

struct CvtArgs {
    const float* s[5];
    u16* d[5];
    int srcn[5];
    int totn[5];
};

__global__ void cvt_multi(CvtArgs a) {
    const int seg = blockIdx.y;
    int i = (blockIdx.x * 256 + threadIdx.x) * 4;
    if (i >= a.totn[seg]) return;
    float4 v = make_float4(0.f, 0.f, 0.f, 0.f);
    if (i < a.srcn[seg]) v = *(const float4*)&a.s[seg][i];
    ushort4 o;
    o.x = f2bf(v.x); o.y = f2bf(v.y); o.z = f2bf(v.z); o.w = f2bf(v.w);
    *(ushort4*)&a.d[seg][i] = o;
}

// ---------------- big GEMM: 256x256, BK=64, 2-buf, 4-phase/K-tile ---------
// C[M,N] = A[M,K] @ W[N,K]^T + bias. 8 waves (2M x 4N), per-wave 128x64.
// Round-2-proven 0-conflict swizzle: LDS slot (row, s) holds global chunk
// s ^ (row&7) (128B rows, 8x16B chunks). Progressive quarter staging with
// vmcnt(6) invariant (drains exactly the whole next K-tile at each tile end).
__device__ __forceinline__ void store_out(u16* C, long idx, float v) { C[idx] = f2bf(v); }
__device__ __forceinline__ void store_out(float* C, long idx, float v) { C[idx] = v; }

template <typename OutT>
__global__ __launch_bounds__(512, 2) void gemm8p(
    const u16* __restrict__ A, const u16* __restrict__ W,
    const float* __restrict__ bias, OutT* __restrict__ C,
    int M, int N, int K) {
    __shared__ __align__(16) u16 As[2][256 * 64];  // 2 x 32KB
    __shared__ __align__(16) u16 Bs[2][256 * 64];

    const int tid = threadIdx.x;
    const int wid = tid >> 6, l = tid & 63;
    const int wr = wid >> 2, wc = wid & 3;      // wave -> (M-half, N-quarter)
    const int l15 = l & 15, lg = l >> 4;

    // XCD-aware bijective swizzle (nwg = 256, % 8 == 0)
    const int lin = blockIdx.y * gridDim.x + blockIdx.x;
    const int cpx = (gridDim.x * gridDim.y) >> 3;
    const int swz = (lin & 7) * cpx + (lin >> 3);
    const long tn = swz % gridDim.x;
    const long tm = swz / gridDim.x;

    const u16* Ab = A + tm * 256 * (long)K;
    const u16* Bb = W + tn * 256 * (long)K;

    // staging: one issue = 512 thr x 16B = 64 rows x 128B (one quarter-tile)
    const int srow = tid >> 3;                       // 0..63 row within quarter
    const int schunk = (tid & 7) ^ (srow & 7);       // pre-swizzled source chunk
    const long srcoff = (long)srow * K + schunk * 8;

    // conflict-free read chunks (element offset within 128B row)
    const int rxor = l15 & 7;
    const int rdo0 = ((0 * 4 + lg) ^ rxor) * 8;
    const int rdo1 = ((1 * 4 + lg) ^ rxor) * 8;

    const int NT = K >> 6;

#define STAGE_A(bufi, q_, t_)                                                 \
    gl_lds16(Ab + (long)(q_)*64 * K + srcoff + (long)(t_)*64,                 \
             &As[bufi][(q_)*4096 + tid * 8])
#define STAGE_B(bufi, q_, t_)                                                 \
    gl_lds16(Bb + (long)(q_)*64 * K + srcoff + (long)(t_)*64,                 \
             &Bs[bufi][(q_)*4096 + tid * 8])

    f32x4 acc[8][4] = {};

    // prologue: tile 0 complete (8 issues) + tile 1 partial {B all, A q0,q2}
#pragma unroll
    for (int q = 0; q < 4; ++q) { STAGE_A(0, q, 0); STAGE_B(0, q, 0); }
#pragma unroll
    for (int q = 0; q < 4; ++q) STAGE_B(1, q, 1);
    STAGE_A(1, 0, 1); STAGE_A(1, 2, 1);
    asm volatile("s_waitcnt vmcnt(6)" ::: "memory");
    __builtin_amdgcn_sched_barrier(0);
    __builtin_amdgcn_s_barrier();

    const int arow = wr * 128 + l15;
    const int brow = wc * 64 + l15;

    for (int t = 0; t < NT; ++t) {
        const int c = t & 1;
        const u16* __restrict__ Ap = &As[c][0];
        const u16* __restrict__ Bp = &Bs[c][0];
        const bool s1 = (t + 1) < NT;
        const bool s2 = (t + 2) < NT;
        bf16x8 b[4][2];

        // ---- phase 0: mf 0-1, load all b ----
        {
            bf16x8 a[2][2];
#pragma unroll
            for (int mi = 0; mi < 2; ++mi) {
                a[mi][0] = *(const bf16x8*)&Ap[(arow + mi * 16) * 64 + rdo0];
                a[mi][1] = *(const bf16x8*)&Ap[(arow + mi * 16) * 64 + rdo1];
            }
#pragma unroll
            for (int nf = 0; nf < 4; ++nf) {
                b[nf][0] = *(const bf16x8*)&Bp[(brow + nf * 16) * 64 + rdo0];
                b[nf][1] = *(const bf16x8*)&Bp[(brow + nf * 16) * 64 + rdo1];
            }
            if (s1) STAGE_A(c ^ 1, 1, t + 1);
            __builtin_amdgcn_s_barrier();
            asm volatile("s_waitcnt lgkmcnt(0)" ::: "memory");
            __builtin_amdgcn_sched_barrier(0);
            __builtin_amdgcn_s_setprio(1);
#pragma unroll
            for (int mi = 0; mi < 2; ++mi)
#pragma unroll
                for (int nf = 0; nf < 4; ++nf) {
                    acc[mi][nf] = mfma16(a[mi][0], b[nf][0], acc[mi][nf]);
                    acc[mi][nf] = mfma16(a[mi][1], b[nf][1], acc[mi][nf]);
                }
            __builtin_amdgcn_s_setprio(0);
            __builtin_amdgcn_s_barrier();
        }
        // ---- phase 1: mf 2-3 ----
        {
            bf16x8 a[2][2];
#pragma unroll
            for (int mi = 0; mi < 2; ++mi) {
                a[mi][0] = *(const bf16x8*)&Ap[(arow + (mi + 2) * 16) * 64 + rdo0];
                a[mi][1] = *(const bf16x8*)&Ap[(arow + (mi + 2) * 16) * 64 + rdo1];
            }
            if (s1) STAGE_A(c ^ 1, 3, t + 1);
            if (s2) { STAGE_B(c, 0, t + 2); STAGE_B(c, 1, t + 2); }
            __builtin_amdgcn_s_barrier();
            asm volatile("s_waitcnt lgkmcnt(0)" ::: "memory");
            __builtin_amdgcn_sched_barrier(0);
            __builtin_amdgcn_s_setprio(1);
#pragma unroll
            for (int mi = 0; mi < 2; ++mi)
#pragma unroll
                for (int nf = 0; nf < 4; ++nf) {
                    acc[mi + 2][nf] = mfma16(a[mi][0], b[nf][0], acc[mi + 2][nf]);
                    acc[mi + 2][nf] = mfma16(a[mi][1], b[nf][1], acc[mi + 2][nf]);
                }
            __builtin_amdgcn_s_setprio(0);
            __builtin_amdgcn_s_barrier();
        }
        // ---- phase 2: mf 4-5 ----
        {
            bf16x8 a[2][2];
#pragma unroll
            for (int mi = 0; mi < 2; ++mi) {
                a[mi][0] = *(const bf16x8*)&Ap[(arow + (mi + 4) * 16) * 64 + rdo0];
                a[mi][1] = *(const bf16x8*)&Ap[(arow + (mi + 4) * 16) * 64 + rdo1];
            }
            if (s2) { STAGE_B(c, 2, t + 2); STAGE_B(c, 3, t + 2); STAGE_A(c, 0, t + 2); }
            __builtin_amdgcn_s_barrier();
            asm volatile("s_waitcnt lgkmcnt(0)" ::: "memory");
            __builtin_amdgcn_sched_barrier(0);
            __builtin_amdgcn_s_setprio(1);
#pragma unroll
            for (int mi = 0; mi < 2; ++mi)
#pragma unroll
                for (int nf = 0; nf < 4; ++nf) {
                    acc[mi + 4][nf] = mfma16(a[mi][0], b[nf][0], acc[mi + 4][nf]);
                    acc[mi + 4][nf] = mfma16(a[mi][1], b[nf][1], acc[mi + 4][nf]);
                }
            __builtin_amdgcn_s_setprio(0);
            __builtin_amdgcn_s_barrier();
        }
        // ---- phase 3: mf 6-7 + end-of-tile counted drain ----
        {
            bf16x8 a[2][2];
#pragma unroll
            for (int mi = 0; mi < 2; ++mi) {
                a[mi][0] = *(const bf16x8*)&Ap[(arow + (mi + 6) * 16) * 64 + rdo0];
                a[mi][1] = *(const bf16x8*)&Ap[(arow + (mi + 6) * 16) * 64 + rdo1];
            }
            if (s2) STAGE_A(c, 2, t + 2);
            __builtin_amdgcn_s_barrier();
            asm volatile("s_waitcnt lgkmcnt(0)" ::: "memory");
            __builtin_amdgcn_sched_barrier(0);
            __builtin_amdgcn_s_setprio(1);
#pragma unroll
            for (int mi = 0; mi < 2; ++mi)
#pragma unroll
                for (int nf = 0; nf < 4; ++nf) {
                    acc[mi + 6][nf] = mfma16(a[mi][0], b[nf][0], acc[mi + 6][nf]);
                    acc[mi + 6][nf] = mfma16(a[mi][1], b[nf][1], acc[mi + 6][nf]);
                }
            __builtin_amdgcn_s_setprio(0);
            if (s2)
                asm volatile("s_waitcnt vmcnt(6)" ::: "memory");
            else
                asm volatile("s_waitcnt vmcnt(0)" ::: "memory");
            __builtin_amdgcn_sched_barrier(0);
            __builtin_amdgcn_s_barrier();
        }
    }
#undef STAGE_A
#undef STAGE_B

    const long row0 = tm * 256 + wr * 128;
    const long col0 = tn * 256 + wc * 64;
    float bv[4];
#pragma unroll
    for (int nf = 0; nf < 4; ++nf) bv[nf] = bias[col0 + nf * 16 + l15];
#pragma unroll
    for (int mf = 0; mf < 8; ++mf)
#pragma unroll
        for (int nf = 0; nf < 4; ++nf)
#pragma unroll
            for (int r = 0; r < 4; ++r) {
                const long row = row0 + mf * 16 + lg * 4 + r;
                const long col = col0 + nf * 16 + l15;
                store_out(C, row * N + col, acc[mf][nf][r] + bv[nf]);
            }
}

// ---------------- small GEMM for K/V projections (m97 128-tile) -----------
__device__ __forceinline__ void gemm128_body(
    const u16* __restrict__ A, const u16* __restrict__ W,
    const float* __restrict__ bias, u16* __restrict__ C,
    int N, int K) {
    __shared__ u16 As[128 * 64];
    __shared__ u16 Bs[128 * 64];
    const int tid = threadIdx.x;
    const int w = tid >> 6, l = tid & 63;
    const int wr = w >> 1, wc = w & 1;
    const int l15 = l & 15, lg = l >> 4;
    const long tm = blockIdx.y, tn = blockIdx.x;
    const u16* Ab = A + tm * 128 * (long)K;
    const u16* Bb = W + tn * 128 * (long)K;

    f32x4 acc[4][4] = {};

    for (int k0 = 0; k0 < K; k0 += 64) {
#pragma unroll
        for (int t = 0; t < 4; ++t) {
            int i = t * 256 + tid;
            int row = i >> 3, cc = i & 7;
            gl_lds16(Ab + (long)row * K + k0 + cc * 8, &As[i * 8]);
            gl_lds16(Bb + (long)row * K + k0 + cc * 8, &Bs[i * 8]);
        }
        __syncthreads();
#pragma unroll
        for (int kk = 0; kk < 64; kk += 32) {
            bf16x8 a[4], b[4];
#pragma unroll
            for (int m = 0; m < 4; ++m)
                a[m] = *(const bf16x8*)&As[(wr * 64 + m * 16 + l15) * 64 + kk + lg * 8];
#pragma unroll
            for (int n = 0; n < 4; ++n)
                b[n] = *(const bf16x8*)&Bs[(wc * 64 + n * 16 + l15) * 64 + kk + lg * 8];
#pragma unroll
            for (int m = 0; m < 4; ++m)
#pragma unroll
                for (int n = 0; n < 4; ++n)
                    acc[m][n] = mfma16(a[m], b[n], acc[m][n]);
        }
        __syncthreads();
    }

    const long row0 = tm * 128 + wr * 64;
    const long col0 = tn * 128 + wc * 64;
#pragma unroll
    for (int m = 0; m < 4; ++m)
#pragma unroll
        for (int n = 0; n < 4; ++n)
#pragma unroll
            for (int r = 0; r < 4; ++r) {
                const long row = row0 + m * 16 + lg * 4 + r;
                const long col = col0 + n * 16 + l15;
                C[row * N + col] = f2bf(acc[m][n][r] + bias[col]);
            }
}

__global__ __launch_bounds__(256) void gemm_kv(
    const u16* __restrict__ A,
    const u16* __restrict__ Wk, const float* __restrict__ bk, u16* __restrict__ Ko,
    const u16* __restrict__ Wv, const float* __restrict__ bv, u16* __restrict__ Vo,
    int N, int K) {
    const bool isv = blockIdx.z != 0;
    gemm128_body(A, isv ? Wv : Wk, isv ? bv : bk, isv ? Vo : Ko, N, K);
}

// ---------------- fused attention ------------------------------------------
__global__ __launch_bounds__(256) void attn_fused(
    const u16* __restrict__ Q,   // [B*4096, 1024] bf16
    const u16* __restrict__ Kb,  // [B*77 (pad 384), 1024] bf16
    const u16* __restrict__ Vb,
    const float* __restrict__ mask,  // [B, 4096, 77] f32
    u16* __restrict__ Ao) {
    __shared__ u16 Ks[96 * 64];
    __shared__ u16 Vt[64 * 96];
    __shared__ u16 Ps[128 * 96];

    const int b = blockIdx.z, h = blockIdx.y, nt = blockIdx.x;
    const int tid = threadIdx.x;
    const int w = tid >> 6, l = tid & 63;
    const int l15 = l & 15, lg = l >> 4;

    for (int c = tid; c < 768; c += 256) {
        const int t = c >> 3, dc = c & 7;
        union { uint4 u; u16 s[8]; } kv, vv;
        kv.u = make_uint4(0, 0, 0, 0);
        vv.u = make_uint4(0, 0, 0, 0);
        if (t < 77) {
            const long base = ((long)(b * 77 + t)) * 1024 + h * 64 + dc * 8;
            kv.u = *(const uint4*)&Kb[base];
            vv.u = *(const uint4*)&Vb[base];
        }
        *(uint4*)&Ks[t * 64 + dc * 8] = kv.u;
#pragma unroll
        for (int j = 0; j < 8; ++j) Vt[(dc * 8 + j) * 96 + t] = vv.s[j];
    }
    __syncthreads();

    f32x4 acc[2][6] = {};
    const long qrow0 = (long)b * 4096 + nt * 128 + w * 32;
#pragma unroll
    for (int kk = 0; kk < 64; kk += 32) {
        bf16x8 a[2], kf[6];
#pragma unroll
        for (int m = 0; m < 2; ++m)
            a[m] = *(const bf16x8*)&Q[(qrow0 + m * 16 + l15) * 1024 + h * 64 + kk + lg * 8];
#pragma unroll
        for (int n = 0; n < 6; ++n)
            kf[n] = *(const bf16x8*)&Ks[(n * 16 + l15) * 64 + kk + lg * 8];
#pragma unroll
        for (int m = 0; m < 2; ++m)
#pragma unroll
            for (int n = 0; n < 6; ++n)
                acc[m][n] = mfma16(a[m], kf[n], acc[m][n]);
    }

    const float* mbase = mask + ((long)b * 4096 + nt * 128 + w * 32) * 77;
#pragma unroll
    for (int m = 0; m < 2; ++m) {
#pragma unroll
        for (int r = 0; r < 4; ++r) {
            const int row = m * 16 + lg * 4 + r;
            float vals[6];
            float rmax = -3e38f;
#pragma unroll
            for (int n = 0; n < 6; ++n) {
                const int col = n * 16 + l15;
                float v = -3e38f;
                if (col < 77) v = acc[m][n][r] * 0.125f + mbase[row * 77 + col];
                vals[n] = v;
                rmax = fmaxf(rmax, v);
            }
#pragma unroll
            for (int off = 1; off < 16; off <<= 1)
                rmax = fmaxf(rmax, __shfl_xor(rmax, off, 64));
            float s = 0.f;
#pragma unroll
            for (int n = 0; n < 6; ++n) {
                float e = (vals[n] > -1e37f) ? __expf(vals[n] - rmax) : 0.f;
                vals[n] = e;
                s += e;
            }
#pragma unroll
            for (int off = 1; off < 16; off <<= 1)
                s += __shfl_xor(s, off, 64);
            const float inv = 1.f / s;
#pragma unroll
            for (int n = 0; n < 6; ++n)
                Ps[(w * 32 + row) * 96 + n * 16 + l15] = f2bf(vals[n] * inv);
        }
    }
    __syncthreads();

    f32x4 o[2][4] = {};
#pragma unroll
    for (int kt = 0; kt < 96; kt += 32) {
        bf16x8 a[2], vf[4];
#pragma unroll
        for (int m = 0; m < 2; ++m)
            a[m] = *(const bf16x8*)&Ps[(w * 32 + m * 16 + l15) * 96 + kt + lg * 8];
#pragma unroll
        for (int n = 0; n < 4; ++n)
            vf[n] = *(const bf16x8*)&Vt[(n * 16 + l15) * 96 + kt + lg * 8];
#pragma unroll
        for (int m = 0; m < 2; ++m)
#pragma unroll
            for (int n = 0; n < 4; ++n)
                o[m][n] = mfma16(a[m], vf[n], o[m][n]);
    }

#pragma unroll
    for (int m = 0; m < 2; ++m)
#pragma unroll
        for (int n = 0; n < 4; ++n)
#pragma unroll
            for (int r = 0; r < 4; ++r) {
                const long row = (long)b * 4096 + nt * 128 + w * 32 + m * 16 + lg * 4 + r;
                const int col = h * 64 + n * 16 + l15;
                Ao[row * 1024 + col] = f2bf(o[m][n][r]);
            }
}

// ---------------- launch ----------------------------------------------------
extern "C" void kernel_launch(void* const* d_in, const int* in_sizes, int n_in,
                              void* d_out, int out_size, void* d_ws, size_t ws_size,
                              hipStream_t stream) {
    const float* hidden = (const float*)d_in[0];
    const float* enc = (const float*)d_in[1];
    const float* mask = (const float*)d_in[2];
    const float* Wq = (const float*)d_in[3];
    const float* bq = (const float*)d_in[4];
    const float* Wk = (const float*)d_in[5];
    const float* bk = (const float*)d_in[6];
    const float* Wv = (const float*)d_in[7];
    const float* bv = (const float*)d_in[8];
    const float* Wo = (const float*)d_in[9];
    const float* bo = (const float*)d_in[10];
    float* out = (float*)d_out;

    char* ws = (char*)d_ws;
    u16* hiddenB = (u16*)(ws);                       // 32 MB
    u16* Qb = (u16*)(ws + 33554432L);                // 32 MB
    u16* AoB = (u16*)(ws + 2 * 33554432L);           // 32 MB
    u16* WqB = (u16*)(ws + 3 * 33554432L);           // 2 MB each
    u16* WkB = WqB + 1048576;
    u16* WvB = WkB + 1048576;
    u16* WoB = WvB + 1048576;
    u16* encB = WoB + 1048576;                       // 384*1024 bf16
    u16* Kbuf = encB + 393216;
    u16* Vbuf = Kbuf + 393216;

    cvt_pad<<<dim3(16384), 256, 0, stream>>>(hidden, hiddenB, 16777216, 16777216);
    CvtArgs ca;
    ca.s[0] = Wq;  ca.d[0] = WqB; ca.srcn[0] = 1048576; ca.totn[0] = 1048576;
    ca.s[1] = Wk;  ca.d[1] = WkB; ca.srcn[1] = 1048576; ca.totn[1] = 1048576;
    ca.s[2] = Wv;  ca.d[2] = WvB; ca.srcn[2] = 1048576; ca.totn[2] = 1048576;
    ca.s[3] = Wo;  ca.d[3] = WoB; ca.srcn[3] = 1048576; ca.totn[3] = 1048576;
    ca.s[4] = enc; ca.d[4] = encB; ca.srcn[4] = 315392; ca.totn[4] = 393216;
    cvt_multi<<<dim3(1024, 5), 256, 0, stream>>>(ca);

    // projections
    gemm8p<u16><<<dim3(4, 64), 512, 0, stream>>>(hiddenB, WqB, bq, Qb, 16384, 1024, 1024);
    gemm_kv<<<dim3(8, 3, 2), 256, 0, stream>>>(encB, WkB, bk, Kbuf, WvB, bv, Vbuf, 1024, 1024);

    attn_fused<<<dim3(32, 16, 4), 256, 0, stream>>>(Qb, Kbuf, Vbuf, mask, AoB);

    gemm8p<float><<<dim3(4, 64), 512, 0, stream>>>(AoB, WoB, bo, out, 16384, 1024, 1024);
}